// Round 15
// baseline (206.250 us; speedup 1.0000x reference)
//
#include <hip/hip_runtime.h>
#include <hip/hip_bf16.h>

// Problem constants
constexpr int B_ = 512;
constexpr int T_ = 128;
constexpr int D_ = 768;
constexpr int CD_ = 192;
constexpr int SD_ = 128;
constexpr int P_ = 128;
constexpr int FEAT_ = 321;   // CD + SD + 1
constexpr float LN_EPS_ = 1e-5f;

constexpr size_t REP_SZ   = (size_t)B_ * 2 * D_;     // 786432 floats
constexpr size_t DN16_FLT = (size_t)P_ * D_ / 2;     // 49152 floats

typedef __attribute__((ext_vector_type(8))) short short8;   // 8 bf16 (4 VGPRs)
typedef __attribute__((ext_vector_type(4))) float f32x4;
typedef unsigned long long ull_t;

__device__ __forceinline__ unsigned short f2bf(float x) {
    unsigned u = __float_as_uint(x);
    return (unsigned short)((u + 0x7FFFu + ((u >> 16) & 1u)) >> 16);
}
__device__ __forceinline__ float bf2f(unsigned short h) {
    return __uint_as_float((unsigned)h << 16);
}

// ---------------------------------------------------------------------------
// Kernel 1: k_pre — blocks 0..127: dirs normalize (bf16); blocks 128..319:
// ortho partials (one Wc row each).
// ---------------------------------------------------------------------------
__global__ __launch_bounds__(256) void k_pre(const float* __restrict__ dirs,
                                             const float* __restrict__ Wc,
                                             const float* __restrict__ Ws,
                                             unsigned short* __restrict__ dn16,
                                             float* __restrict__ part) {
    int tid = threadIdx.x;
    if (blockIdx.x < 128) {
        int p = blockIdx.x;
        float s = 0.f;
        for (int d = tid; d < D_; d += 256) {
            float v = dirs[(size_t)p * D_ + d];
            s = fmaf(v, v, s);
        }
        __shared__ float red[256];
        red[tid] = s;
        __syncthreads();
        for (int off = 128; off > 0; off >>= 1) {
            if (tid < off) red[tid] += red[tid + off];
            __syncthreads();
        }
        float inv = 1.0f / sqrtf(red[0]);
        for (int d = tid; d < D_; d += 256) {
            dn16[(size_t)p * D_ + d] = f2bf(dirs[(size_t)p * D_ + d] * inv);
        }
    } else {
        int i = blockIdx.x - 128;    // Wc row, 0..191
        __shared__ float wrow[1536];
        __shared__ float tmp[256];
        for (int k = tid; k < 1536; k += 256) wrow[k] = Wc[(size_t)i * 1536 + k];
        __syncthreads();
        int j = tid & 127, h = tid >> 7;
        const float* wsr = Ws + (size_t)j * 1536 + h * 768;
        const float* wr = wrow + h * 768;
        float s = 0.f;
        for (int k = 0; k < 768; ++k) s = fmaf(wr[k], wsr[k], s);
        tmp[tid] = s;
        __syncthreads();
        if (tid < 128) {
            float d = tmp[tid] + tmp[tid + 128];
            tmp[tid] = d * d;
        }
        __syncthreads();
        for (int off = 64; off > 0; off >>= 1) {
            if (tid < off) tmp[tid] += tmp[tid + off];
            __syncthreads();
        }
        if (tid == 0) part[i] = tmp[0];
    }
}

// ---------------------------------------------------------------------------
// Kernel 2: monolithic 128x128 MFMA GEMM, KB=64 single stage buffer,
// 2 barriers per K-step (24 total, was 48), reg prefetch (2 named sets),
// fused rep (gather mask-MFMA) + key-rank + paired diff.
// LDS 51712 -> 3 blocks/CU. 512 threads, one block per batch.
// ---------------------------------------------------------------------------
constexpr int NIT_ = 12;            // 768 / 64

__global__ __launch_bounds__(512) void k_projsort(const float* __restrict__ H,
                                                  const int* __restrict__ tt,
                                                  const int* __restrict__ attn,
                                                  const unsigned short* __restrict__ dn16,
                                                  float* __restrict__ rep,
                                                  float* __restrict__ d_ot) {
    const int b = blockIdx.x;
    const int tid = threadIdx.x;
    const int lane = tid & 63;
    const int w = tid >> 6;           // wave 0..7
    const int wr = w >> 2;            // t-row half
    const int wc = w & 3;             // p-col quarter
    const int fr = lane & 15;
    const int kg = lane >> 4;

    __shared__ __align__(16) unsigned short stage[16384];   // 32 KB: A[128][64] + B[128][64]
    __shared__ unsigned char xb[8192];                       // [64][128]
    __shared__ unsigned char yb[8192];
    __shared__ float dred[512];                              // + ballot exchange overlay
    __shared__ unsigned short mask16[256];                   // bf16 mask rows
    unsigned short* proj16 = stage;                          // overlay post-GEMM
    ull_t* xch = (ull_t*)dred;

    // --- staging geometry (3-bit chunk swizzle, source pre-swizzled) ---
    const float* Hb = H + (size_t)b * T_ * D_;
    const int srow = tid >> 2;                  // 0..127
    const int c4   = tid & 3;                   // base chunk 0..3
    const int swz  = (srow >> 1) & 7;           // 3-bit row swizzle
    const int p0c  = c4;                        // phys chunk 0
    const int p1c  = c4 + 4;                    // phys chunk 1
    const int l0c  = p0c ^ swz;                 // logical chunks
    const int l1c  = p1c ^ swz;
    const float* gA0 = Hb + (size_t)srow * D_ + l0c * 8;
    const float* gA1 = Hb + (size_t)srow * D_ + l1c * 8;
    const unsigned short* gB0 = dn16 + (size_t)srow * D_ + l0c * 8;
    const unsigned short* gB1 = dn16 + (size_t)srow * D_ + l1c * 8;
    const int wOffA0 = srow * 64 + p0c * 8;
    const int wOffA1 = srow * 64 + p1c * 8;
    const int wOffB0 = 8192 + wOffA0;
    const int wOffB1 = 8192 + wOffA1;

    // prologue: prefetch iters 0 (set A) and 1 (set B)
    float4 x0A = *reinterpret_cast<const float4*>(gA0);
    float4 x1A = *reinterpret_cast<const float4*>(gA0 + 4);
    float4 x2A = *reinterpret_cast<const float4*>(gA1);
    float4 x3A = *reinterpret_cast<const float4*>(gA1 + 4);
    short8 v0A = *reinterpret_cast<const short8*>(gB0);
    short8 v1A = *reinterpret_cast<const short8*>(gB1);
    float4 x0B = *reinterpret_cast<const float4*>(gA0 + 64);
    float4 x1B = *reinterpret_cast<const float4*>(gA0 + 68);
    float4 x2B = *reinterpret_cast<const float4*>(gA1 + 64);
    float4 x3B = *reinterpret_cast<const float4*>(gA1 + 68);
    short8 v0B = *reinterpret_cast<const short8*>(gB0 + 64);
    short8 v1B = *reinterpret_cast<const short8*>(gB1 + 64);

    // --- phase 0: masks via ballot, counts, per-row pos, mask rows ---
    const int myt = 64 * wr + lane;
    int vt = tt[b * T_ + myt];
    int va = attn[b * T_ + myt];
    bool m0 = (vt == 0) && (va == 1);
    bool m1 = (vt == 1) && (va == 1);
    ull_t bal0 = __ballot(m0);
    ull_t bal1 = __ballot(m1);
    if (lane == 0 && (w == 0 || w == 4)) {
        xch[wr * 2] = bal0;
        xch[wr * 2 + 1] = bal1;
    }
    if (tid < 128) {
        int t2 = tt[b * T_ + tid];
        int a2 = attn[b * T_ + tid];
        mask16[tid]       = (t2 == 0 && a2 == 1) ? 0x3F80u : 0u;
        mask16[128 + tid] = (t2 == 1 && a2 == 1) ? 0x3F80u : 0u;
    }
    __syncthreads();
    const ull_t lo0 = xch[0], lo1 = xch[1], hi0 = xch[2], hi1 = xch[3];
    const int n0 = __popcll(lo0) + __popcll(hi0);
    const int n1 = __popcll(lo1) + __popcll(hi1);
    const int ntot = n0 + n1;
    const float inv0 = 1.f / (float)max(n0, 1);
    const float inv1 = 1.f / (float)max(n1, 1);
    ull_t below = (1ull << lane) - 1ull;
    int mypos = 0xFF;
    if (m0) mypos = (wr ? __popcll(lo0) : 0) + __popcll((wr ? hi0 : lo0) & below);
    else if (m1) mypos = n0 + (wr ? __popcll(lo1) : 0) + __popcll((wr ? hi1 : lo1) & below);
    __syncthreads();   // xch consumed; mask16 visible

    // --- frag addresses (kc=0; kc=1 = addr ^ 32) ---
    int addrA[4], addrB[2];
#pragma unroll
    for (int m = 0; m < 4; ++m) {
        int row = 64 * wr + 16 * m + fr;
        addrA[m] = row * 64 + (kg ^ ((row >> 1) & 7)) * 8;
    }
#pragma unroll
    for (int n = 0; n < 2; ++n) {
        int row = 32 * wc + 16 * n + fr;
        addrB[n] = 8192 + row * 64 + (kg ^ ((row >> 1) & 7)) * 8;
    }
    // rep gather geometry (duty waves 0,1,4,5)
    const bool duty = (w == 0 || w == 1 || w == 4 || w == 5);
    const int kcr = w >> 2;           // k-half this duty wave covers
    const int grp = w & 1;            // 16-d half within the k-half
    const int dk = kcr * 32 + grp * 16 + fr;   // dim within 64-k tile
    const int glc = dk >> 3, gsub = dk & 7;    // logical chunk + sub-offset
    float* repb = rep + (size_t)b * 2 * D_;

    f32x4 acc[4][2];
#pragma unroll
    for (int m = 0; m < 4; ++m)
#pragma unroll
        for (int n = 0; n < 2; ++n) acc[m][n] = (f32x4){0.f, 0.f, 0.f, 0.f};

    auto body = [&](int it, float4& pa0, float4& pa1, float4& pa2, float4& pa3,
                    short8& pb0, short8& pb1) {
        // convert + stage current tile
        short8 wv0, wv1;
        wv0[0] = (short)f2bf(pa0.x); wv0[1] = (short)f2bf(pa0.y);
        wv0[2] = (short)f2bf(pa0.z); wv0[3] = (short)f2bf(pa0.w);
        wv0[4] = (short)f2bf(pa1.x); wv0[5] = (short)f2bf(pa1.y);
        wv0[6] = (short)f2bf(pa1.z); wv0[7] = (short)f2bf(pa1.w);
        wv1[0] = (short)f2bf(pa2.x); wv1[1] = (short)f2bf(pa2.y);
        wv1[2] = (short)f2bf(pa2.z); wv1[3] = (short)f2bf(pa2.w);
        wv1[4] = (short)f2bf(pa3.x); wv1[5] = (short)f2bf(pa3.y);
        wv1[6] = (short)f2bf(pa3.z); wv1[7] = (short)f2bf(pa3.w);
        *reinterpret_cast<short8*>(&stage[wOffA0]) = wv0;
        *reinterpret_cast<short8*>(&stage[wOffA1]) = wv1;
        *reinterpret_cast<short8*>(&stage[wOffB0]) = pb0;
        *reinterpret_cast<short8*>(&stage[wOffB1]) = pb1;
        if (srow == 0) {   // cls = H[b,0,:] exact fp32
            float* cd = repb + it * 64;
            *reinterpret_cast<float4*>(cd + l0c * 8)     = pa0;
            *reinterpret_cast<float4*>(cd + l0c * 8 + 4) = pa1;
            *reinterpret_cast<float4*>(cd + l1c * 8)     = pa2;
            *reinterpret_cast<float4*>(cd + l1c * 8 + 4) = pa3;
        }
        if (it + 2 < NIT_) {   // refill this reg set (consumed 2 iters later)
            int k = (it + 2) * 64;
            pa0 = *reinterpret_cast<const float4*>(gA0 + k);
            pa1 = *reinterpret_cast<const float4*>(gA0 + k + 4);
            pa2 = *reinterpret_cast<const float4*>(gA1 + k);
            pa3 = *reinterpret_cast<const float4*>(gA1 + k + 4);
            pb0 = *reinterpret_cast<const short8*>(gB0 + k);
            pb1 = *reinterpret_cast<const short8*>(gB1 + k);
        }
        asm volatile("s_waitcnt lgkmcnt(0)" ::: "memory");
        __builtin_amdgcn_s_barrier();
        asm volatile("" ::: "memory");

        // kc = 0
        {
            short8 af[4], bf_[2];
#pragma unroll
            for (int m = 0; m < 4; ++m)
                af[m] = *reinterpret_cast<const short8*>(&stage[addrA[m]]);
#pragma unroll
            for (int n = 0; n < 2; ++n)
                bf_[n] = *reinterpret_cast<const short8*>(&stage[addrB[n]]);
#pragma unroll
            for (int m = 0; m < 4; ++m)
#pragma unroll
                for (int n = 0; n < 2; ++n)
                    acc[m][n] = __builtin_amdgcn_mfma_f32_16x16x32_bf16(af[m], bf_[n], acc[m][n], 0, 0, 0);
        }
        // kc = 1 (chunk bit2 flip -> addr ^ 32)
        {
            short8 af[4], bf_[2];
#pragma unroll
            for (int m = 0; m < 4; ++m)
                af[m] = *reinterpret_cast<const short8*>(&stage[addrA[m] ^ 32]);
#pragma unroll
            for (int n = 0; n < 2; ++n)
                bf_[n] = *reinterpret_cast<const short8*>(&stage[addrB[n] ^ 32]);
#pragma unroll
            for (int m = 0; m < 4; ++m)
#pragma unroll
                for (int n = 0; n < 2; ++n)
                    acc[m][n] = __builtin_amdgcn_mfma_f32_16x16x32_bf16(af[m], bf_[n], acc[m][n], 0, 0, 0);
        }

        // fused rep: 4 duty waves, contraction over t via mask-MFMA gather
        if (duty) {
            f32x4 ar = (f32x4){0.f, 0.f, 0.f, 0.f};
#pragma unroll
            for (int tc = 0; tc < 4; ++tc) {
                int tbase = tc * 32 + kg * 8;
                short8 am = {0, 0, 0, 0, 0, 0, 0, 0};
                if (fr < 2) am = *reinterpret_cast<const short8*>(&mask16[fr * 128 + tbase]);
                short8 bm;
#pragma unroll
                for (int j = 0; j < 8; ++j) {
                    int t = tbase + j;
                    bm[j] = (short)stage[t * 64 + (glc ^ ((t >> 1) & 7)) * 8 + gsub];
                }
                ar = __builtin_amdgcn_mfma_f32_16x16x32_bf16(am, bm, ar, 0, 0, 0);
            }
            if (lane < 16)
                repb[D_ + it * 64 + dk] = ar[0] * inv0 - ar[1] * inv1;
        }
        asm volatile("" ::: "memory");
        __builtin_amdgcn_s_barrier();
        asm volatile("" ::: "memory");
    };

    for (int mi = 0; mi < NIT_ / 2; ++mi) {
        body(2 * mi,     x0A, x1A, x2A, x3A, v0A, v1A);
        body(2 * mi + 1, x0B, x1B, x2B, x3B, v0B, v1B);
    }
    __syncthreads();   // all reads drained; stage dead -> proj16 overlay

    // --- epilogue: proj16[pos[t]][p] as sortable u16 (pos via shfl) ---
#pragma unroll
    for (int m = 0; m < 4; ++m) {
#pragma unroll
        for (int r = 0; r < 4; ++r) {
            int rowlane = 16 * m + kg * 4 + r;
            int pp = __shfl(mypos, rowlane);
            if (pp != 0xFF) {
#pragma unroll
                for (int n = 0; n < 2; ++n) {
                    int col = 32 * wc + 16 * n + fr;
                    unsigned bb = f2bf(acc[m][n][r]);
                    unsigned su = bb ^ ((bb >> 15) ? 0xFFFFu : 0x8000u);
                    proj16[pp * 128 + col] = (unsigned short)su;
                }
            }
        }
    }
    __syncthreads();

    // --- phase 2: ranking via sortable-u32 keys, 2 passes x 16 keys ---
    const int mmv = min(n0, n1);      // <= 64 since n0+n1 <= 128
    const int c = tid & 127;
    const int q = tid >> 7;           // 0..3
#pragma unroll
    for (int pass = 0; pass < 2; ++pass) {
        const int pbase = q * 32 + pass * 16;
        unsigned kv[16];
        int cnt[16];
#pragma unroll
        for (int ii = 0; ii < 16; ++ii) {
            int p = pbase + ii;
            unsigned key = 0xFFFFFFFFu;
            if (p < ntot) {
                unsigned su = proj16[p * 128 + c];
                key = ((unsigned)(p >= n0) << 31) | (su << 8) | (unsigned)p;
            }
            kv[ii] = key;
            cnt[ii] = 0;
        }
        int lo, hi;
        if (pbase + 16 <= n0) { lo = 0;  hi = n0;   }
        else if (pbase >= n0) { lo = n0; hi = ntot; }
        else                  { lo = 0;  hi = ntot; }
        for (int j = lo; j < hi; ++j) {
            unsigned su = proj16[j * 128 + c];
            unsigned kw = ((unsigned)(j >= n0) << 31) | (su << 8) | (unsigned)j;
#pragma unroll
            for (int ii = 0; ii < 16; ++ii) cnt[ii] += (kw < kv[ii]) ? 1 : 0;
        }
#pragma unroll
        for (int ii = 0; ii < 16; ++ii) {
            int p = pbase + ii;
            if (p < ntot) {
                int rank = cnt[ii] - ((p >= n0 && lo == 0) ? n0 : 0);
                if (rank < mmv) {
                    unsigned char* buf = (p >= n0) ? yb : xb;
                    buf[rank * 128 + c] = (unsigned char)p;
                }
            }
        }
    }
    __syncthreads();

    // --- phase 3: paired diff per column, max over columns ---
    float part = 0.f;
    for (int r = q; r < mmv; r += 4) {
        unsigned sx = proj16[(int)xb[r * 128 + c] * 128 + c];
        unsigned sy = proj16[(int)yb[r * 128 + c] * 128 + c];
        unsigned bx = sx ^ ((sx >> 15) ? 0x8000u : 0xFFFFu);
        unsigned byv = sy ^ ((sy >> 15) ? 0x8000u : 0xFFFFu);
        part += fabsf(bf2f((unsigned short)bx) - bf2f((unsigned short)byv));
    }
    dred[tid] = part;
    __syncthreads();
    if (tid < 128) {
        float invm = 1.f / (float)max(mmv, 1);
        dred[tid] = (dred[tid] + dred[tid + 128] + dred[tid + 256] + dred[tid + 384]) * invm;
    }
    __syncthreads();
    if (tid < 64) {
        float m = fmaxf(dred[tid], dred[tid + 64]);
#pragma unroll
        for (int off = 32; off > 0; off >>= 1) m = fmaxf(m, __shfl_xor(m, off));
        if (tid == 0) d_ot[b] = m;
    }
}

// ---------------------------------------------------------------------------
// Kernel 3: head — C/S GEMV + gate + LayerNorm + logits; block 0 also
// finalizes ortho (part[] ready via stream order). 4 batches/block.
// ---------------------------------------------------------------------------
__global__ __launch_bounds__(320) void k_head(const float* __restrict__ rep,
                                              const float* __restrict__ Wc,
                                              const float* __restrict__ bc,
                                              const float* __restrict__ Ws,
                                              const float* __restrict__ bs,
                                              const float* __restrict__ gate,
                                              const float* __restrict__ lng,
                                              const float* __restrict__ lnb,
                                              const float* __restrict__ Wcls,
                                              const float* __restrict__ bcls,
                                              const float* __restrict__ d_ot,
                                              const float* __restrict__ part,
                                              float* __restrict__ out) {
    int b0 = blockIdx.x * 4;
    int tid = threadIdx.x;
    __shared__ __align__(16) float repS[4 * 1536];
    __shared__ float featS[4 * FEAT_];
    __shared__ float ored[256];

    const float4* repg = reinterpret_cast<const float4*>(rep + (size_t)b0 * 1536);
    float4* repl = reinterpret_cast<float4*>(repS);
    for (int i = tid; i < 1536; i += 320) repl[i] = repg[i];
    __syncthreads();

    float g = 1.f / (1.f + expf(-gate[0]));

    {
        int o = tid;  // 0..319
        bool isC = o < CD_;
        const float* wptr = isC ? (Wc + (size_t)o * 1536) : (Ws + (size_t)(o - CD_) * 1536);
        float bias = isC ? bc[o] : bs[o - CD_];
        float scale = isC ? (1.f - g) : g;
        const float4* w4 = reinterpret_cast<const float4*>(wptr);
        float a0 = 0.f, a1 = 0.f, a2 = 0.f, a3 = 0.f;
        for (int k4 = 0; k4 < 384; ++k4) {
            float4 wv = w4[k4];
            float4 r0 = repl[k4];
            float4 r1 = repl[384 + k4];
            float4 r2 = repl[768 + k4];
            float4 r3 = repl[1152 + k4];
            a0 += fmaf(wv.x, r0.x, fmaf(wv.y, r0.y, fmaf(wv.z, r0.z, wv.w * r0.w)));
            a1 += fmaf(wv.x, r1.x, fmaf(wv.y, r1.y, fmaf(wv.z, r1.z, wv.w * r1.w)));
            a2 += fmaf(wv.x, r2.x, fmaf(wv.y, r2.y, fmaf(wv.z, r2.z, wv.w * r2.w)));
            a3 += fmaf(wv.x, r3.x, fmaf(wv.y, r3.y, fmaf(wv.z, r3.z, wv.w * r3.w)));
        }
        featS[0 * FEAT_ + o] = (a0 + bias) * scale;
        featS[1 * FEAT_ + o] = (a1 + bias) * scale;
        featS[2 * FEAT_ + o] = (a2 + bias) * scale;
        featS[3 * FEAT_ + o] = (a3 + bias) * scale;
    }
    if (tid < 4) featS[tid * FEAT_ + 320] = d_ot[b0 + tid];
    __syncthreads();

    int w = tid >> 6, lane = tid & 63;
    if (w < 4) {   // wave w handles batch b0+w
        const float* f = featS + w * FEAT_;
        float s = 0.f, s2 = 0.f;
        for (int i = lane; i < FEAT_; i += 64) {
            float v = f[i];
            s += v;
            s2 = fmaf(v, v, s2);
        }
#pragma unroll
        for (int off = 32; off > 0; off >>= 1) {
            s += __shfl_xor(s, off);
            s2 += __shfl_xor(s2, off);
        }
        float mu = s * (1.f / (float)FEAT_);
        float var = fmaxf(s2 * (1.f / (float)FEAT_) - mu * mu, 0.f);
        float rstd = 1.0f / sqrtf(var + LN_EPS_);
        float l0 = 0.f, l1 = 0.f;
        for (int i = lane; i < FEAT_; i += 64) {
            float nv = (f[i] - mu) * rstd * lng[i] + lnb[i];
            l0 = fmaf(nv, Wcls[i], l0);
            l1 = fmaf(nv, Wcls[FEAT_ + i], l1);
        }
#pragma unroll
        for (int off = 32; off > 0; off >>= 1) {
            l0 += __shfl_xor(l0, off);
            l1 += __shfl_xor(l1, off);
        }
        if (lane == 0) {
            out[(size_t)(b0 + w) * 2 + 0] = l0 + bcls[0];
            out[(size_t)(b0 + w) * 2 + 1] = l1 + bcls[1];
        }
    }

    // ortho finalize (block 0): sum part[0..191] / (CD*SD)
    if (blockIdx.x == 0) {
        __syncthreads();
        if (tid < 256) {
            ored[tid] = (tid < CD_) ? part[tid] : 0.f;
        }
        __syncthreads();
        if (tid < 256) {
            for (int off = 128; off > 0; off >>= 1) {
                if (tid < off) ored[tid] += ored[tid + off];
                __syncthreads();
            }
            if (tid == 0) out[(size_t)B_ * 2] = ored[0] / (float)(CD_ * SD_);
        }
    }
}

// ---------------------------------------------------------------------------
extern "C" void kernel_launch(void* const* d_in, const int* in_sizes, int n_in,
                              void* d_out, int out_size, void* d_ws, size_t ws_size,
                              hipStream_t stream) {
    const float* H    = (const float*)d_in[0];
    const int*   tt   = (const int*)d_in[1];
    const int*   attn = (const int*)d_in[2];
    const float* Wc   = (const float*)d_in[3];
    const float* bc   = (const float*)d_in[4];
    const float* Ws   = (const float*)d_in[5];
    const float* bs   = (const float*)d_in[6];
    const float* gate = (const float*)d_in[7];
    const float* lng  = (const float*)d_in[8];
    const float* lnb  = (const float*)d_in[9];
    const float* Wcls = (const float*)d_in[10];
    const float* bcls = (const float*)d_in[11];
    const float* dirs = (const float*)d_in[12];

    float* ws    = (float*)d_ws;
    float* rep   = ws;                                      // [B][1536] fp32
    unsigned short* dn16 = (unsigned short*)(ws + REP_SZ);  // [P][D] bf16 row-major
    float* dot   = ws + REP_SZ + DN16_FLT;                  // [B]
    float* part  = dot + B_;                                // [CD]
    float* out   = (float*)d_out;

    k_pre<<<320, 256, 0, stream>>>(dirs, Wc, Ws, dn16, part);
    k_projsort<<<B_, 512, 0, stream>>>(H, tt, attn, dn16, rep, dot);
    k_head<<<B_ / 4, 320, 0, stream>>>(rep, Wc, bc, Ws, bs, gate, lng, lnb, Wcls, bcls, dot, part, out);
}

// Round 16
// 187.702 us; speedup vs baseline: 1.0988x; 1.0988x over previous
//
#include <hip/hip_runtime.h>
#include <hip/hip_bf16.h>

// Problem constants
constexpr int B_ = 512;
constexpr int T_ = 128;
constexpr int D_ = 768;
constexpr int CD_ = 192;
constexpr int SD_ = 128;
constexpr int P_ = 128;
constexpr int FEAT_ = 321;   // CD + SD + 1
constexpr float LN_EPS_ = 1e-5f;

constexpr size_t REP_SZ   = (size_t)B_ * 2 * D_;     // 786432 floats
constexpr size_t DN16_FLT = (size_t)P_ * D_ / 2;     // 49152 floats

typedef __attribute__((ext_vector_type(8))) short short8;   // 8 bf16 (4 VGPRs)
typedef __attribute__((ext_vector_type(4))) float f32x4;
typedef unsigned long long ull_t;

__device__ __forceinline__ unsigned short f2bf(float x) {
    unsigned u = __float_as_uint(x);
    return (unsigned short)((u + 0x7FFFu + ((u >> 16) & 1u)) >> 16);
}
__device__ __forceinline__ float bf2f(unsigned short h) {
    return __uint_as_float((unsigned)h << 16);
}

// ---------------------------------------------------------------------------
// Kernel 1: dirs_n = dirs / ||dirs||, bf16, row-major
// ---------------------------------------------------------------------------
__global__ __launch_bounds__(256) void k_dirs(const float* __restrict__ dirs,
                                              unsigned short* __restrict__ dn16) {
    int p = blockIdx.x;
    int tid = threadIdx.x;
    float s = 0.f;
    for (int d = tid; d < D_; d += 256) {
        float v = dirs[(size_t)p * D_ + d];
        s = fmaf(v, v, s);
    }
    __shared__ float red[256];
    red[tid] = s;
    __syncthreads();
    for (int off = 128; off > 0; off >>= 1) {
        if (tid < off) red[tid] += red[tid + off];
        __syncthreads();
    }
    float inv = 1.0f / sqrtf(red[0]);
    for (int d = tid; d < D_; d += 256) {
        dn16[(size_t)p * D_ + d] = f2bf(dirs[(size_t)p * D_ + d] * inv);
    }
}

// ---------------------------------------------------------------------------
// Kernel 2: r14-winner monolithic 128x128 MFMA GEMM (depth-2 reg prefetch,
// dbuf LDS, compiler-tracked waits) with ONE barrier per K-step (WAR proof:
// body(i+2)'s buf writes follow barrier1(i+1), and every wave's lgkmcnt(0)
// before that barrier drains its body(i) reads) + fused rep (gather
// mask-MFMA) + key-rank + paired diff. proj16 overlays stage -> LDS 51712.
// 512 threads, one block per batch.
// ---------------------------------------------------------------------------
constexpr int NIT_ = 24;            // 768 / 32
constexpr int BUF_U16_ = 8192;      // A 4096 + B 4096 u16 per buffer (16 KB)

__global__ __launch_bounds__(512) void k_projsort(const float* __restrict__ H,
                                                  const int* __restrict__ tt,
                                                  const int* __restrict__ attn,
                                                  const unsigned short* __restrict__ dn16,
                                                  float* __restrict__ rep,
                                                  float* __restrict__ d_ot) {
    const int b = blockIdx.x;
    const int tid = threadIdx.x;
    const int lane = tid & 63;
    const int w = tid >> 6;           // wave 0..7
    const int wr = w >> 2;            // t-row half
    const int wc = w & 3;             // p-col quarter
    const int fr = lane & 15;
    const int kg = lane >> 4;

    __shared__ __align__(16) unsigned short stage[2 * BUF_U16_];  // 32 KB; proj16 overlay post-GEMM
    __shared__ unsigned char xb[8192];                            // [64][128]
    __shared__ unsigned char yb[8192];
    __shared__ float dred[512];                                   // + ballot exchange overlay
    __shared__ unsigned short mask16[256];                        // bf16 mask rows
    unsigned short* proj16 = stage;
    ull_t* xch = (ull_t*)dred;

    // --- staging geometry; issue depth-2 prefetch ASAP ---
    const float* Hb = H + (size_t)b * T_ * D_;
    const int srow = tid >> 2;                 // 0..127
    const int scp  = tid & 3;                  // phys 16B chunk (8 u16)
    const int sclog = scp ^ ((srow >> 1) & 3); // logical chunk (source pre-swizzle)
    const float* gA = Hb + (size_t)srow * D_ + sclog * 8;
    const unsigned short* gB = dn16 + (size_t)srow * D_ + sclog * 8;
    const int dOffA = srow * 32 + scp * 8;
    const int dOffB = 4096 + dOffA;

    float4 a0A = *reinterpret_cast<const float4*>(gA);
    float4 a1A = *reinterpret_cast<const float4*>(gA + 4);
    short8 bvA = *reinterpret_cast<const short8*>(gB);
    float4 a0B = *reinterpret_cast<const float4*>(gA + 32);
    float4 a1B = *reinterpret_cast<const float4*>(gA + 36);
    short8 bvB = *reinterpret_cast<const short8*>(gB + 32);

    // --- phase 0: masks via ballot, counts, per-row pos (regs), mask rows ---
    const int myt = 64 * wr + lane;
    int vt = tt[b * T_ + myt];
    int va = attn[b * T_ + myt];
    bool m0 = (vt == 0) && (va == 1);
    bool m1 = (vt == 1) && (va == 1);
    ull_t bal0 = __ballot(m0);
    ull_t bal1 = __ballot(m1);
    if (lane == 0 && (w == 0 || w == 4)) {
        xch[wr * 2] = bal0;
        xch[wr * 2 + 1] = bal1;
    }
    if (tid < 128) {
        int t2 = tt[b * T_ + tid];
        int a2 = attn[b * T_ + tid];
        mask16[tid]       = (t2 == 0 && a2 == 1) ? 0x3F80u : 0u;
        mask16[128 + tid] = (t2 == 1 && a2 == 1) ? 0x3F80u : 0u;
    }
    __syncthreads();
    const ull_t lo0 = xch[0], lo1 = xch[1], hi0 = xch[2], hi1 = xch[3];
    const int n0 = __popcll(lo0) + __popcll(hi0);
    const int n1 = __popcll(lo1) + __popcll(hi1);
    const int ntot = n0 + n1;
    const float inv0 = 1.f / (float)max(n0, 1);
    const float inv1 = 1.f / (float)max(n1, 1);
    ull_t below = (1ull << lane) - 1ull;
    int mypos = 0xFF;
    if (m0) mypos = (wr ? __popcll(lo0) : 0) + __popcll((wr ? hi0 : lo0) & below);
    else if (m1) mypos = n0 + (wr ? __popcll(lo1) : 0) + __popcll((wr ? hi1 : lo1) & below);
    __syncthreads();   // xch consumed before dred reuse; mask16 visible

    // --- phase 1: GEMM (1 barrier/iter) + fused rep (gather mask-MFMA) ---
    const int ck = (kg ^ ((fr >> 1) & 3)) * 8;           // swizzled k-chunk
    const int baseA = (64 * wr + fr) * 32 + ck;          // + 512*m
    const int baseB = 4096 + (32 * wc + fr) * 32 + ck;   // + 512*n
    const int grp = w & 1;            // rep d-half for duty waves
    const int dl = grp * 16 + fr;
    const int dch = dl >> 3, dsub = dl & 7;
    float* repb = rep + (size_t)b * 2 * D_;

    f32x4 acc[4][2];
#pragma unroll
    for (int m = 0; m < 4; ++m)
#pragma unroll
        for (int n = 0; n < 2; ++n) acc[m][n] = (f32x4){0.f, 0.f, 0.f, 0.f};

    auto body = [&](int it, unsigned short* sb, float4& pa0, float4& pa1, short8& pbv) {
        // convert + stage current tile (compiler waits the pa/pbv vmcnt deps)
        short8 wv;
        wv[0] = (short)f2bf(pa0.x); wv[1] = (short)f2bf(pa0.y);
        wv[2] = (short)f2bf(pa0.z); wv[3] = (short)f2bf(pa0.w);
        wv[4] = (short)f2bf(pa1.x); wv[5] = (short)f2bf(pa1.y);
        wv[6] = (short)f2bf(pa1.z); wv[7] = (short)f2bf(pa1.w);
        *reinterpret_cast<short8*>(sb + dOffA) = wv;
        *reinterpret_cast<short8*>(sb + dOffB) = pbv;
        if (srow == 0) {   // cls = H[b,0,:] exact fp32
            float* cd = repb + it * 32 + sclog * 8;
            *reinterpret_cast<float4*>(cd)     = pa0;
            *reinterpret_cast<float4*>(cd + 4) = pa1;
        }
        if (it + 2 < NIT_) {   // depth-2 prefetch, in flight across barrier+MFMA
            int k = (it + 2) * 32;
            pa0 = *reinterpret_cast<const float4*>(gA + k);
            pa1 = *reinterpret_cast<const float4*>(gA + k + 4);
            pbv = *reinterpret_cast<const short8*>(gB + k);
        }
        // Drain own ds ops (this iter's writes AND prev-iter's reads), then
        // the single barrier: RAW for buf(it), WAR for buf(it) vs body(it+2).
        asm volatile("s_waitcnt lgkmcnt(0)" ::: "memory");
        __builtin_amdgcn_s_barrier();
        asm volatile("" ::: "memory");

        short8 af[4], bf_[2];
#pragma unroll
        for (int m = 0; m < 4; ++m)
            af[m] = *reinterpret_cast<const short8*>(sb + baseA + 512 * m);
#pragma unroll
        for (int n = 0; n < 2; ++n)
            bf_[n] = *reinterpret_cast<const short8*>(sb + baseB + 512 * n);
#pragma unroll
        for (int m = 0; m < 4; ++m)
#pragma unroll
            for (int n = 0; n < 2; ++n)
                acc[m][n] = __builtin_amdgcn_mfma_f32_16x16x32_bf16(af[m], bf_[n], acc[m][n], 0, 0, 0);

        // fused rep: duty = 2 waves per parity; contraction over t via mask-MFMA
        bool duty = ((it & 1) == 0) ? (w == 0 || w == 1) : (w == 4 || w == 5);
        if (duty) {
            f32x4 ar = (f32x4){0.f, 0.f, 0.f, 0.f};
#pragma unroll
            for (int tc = 0; tc < 4; ++tc) {
                int tbase = tc * 32 + kg * 8;
                short8 am = {0, 0, 0, 0, 0, 0, 0, 0};
                if (fr < 2) am = *reinterpret_cast<const short8*>(&mask16[fr * 128 + tbase]);
                short8 bm;
#pragma unroll
                for (int j = 0; j < 8; ++j) {
                    int t = tbase + j;
                    bm[j] = (short)sb[t * 32 + (dch ^ ((t >> 1) & 3)) * 8 + dsub];
                }
                ar = __builtin_amdgcn_mfma_f32_16x16x32_bf16(am, bm, ar, 0, 0, 0);
            }
            if (lane < 16)
                repb[D_ + it * 32 + grp * 16 + lane] = ar[0] * inv0 - ar[1] * inv1;
        }
        // NOTE: no second barrier — WAR is covered by the next iteration's
        // lgkmcnt(0)+barrier (each wave drains its reads before passing it).
    };

    for (int mi = 0; mi < NIT_ / 2; ++mi) {
        body(2 * mi,     stage,            a0A, a1A, bvA);
        body(2 * mi + 1, stage + BUF_U16_, a0B, a1B, bvB);
    }
    __syncthreads();   // all frag/gather reads drained; stage now dead -> proj16 overlay

    // --- epilogue: proj16[pos[t]][p] as sortable u16 (pos via shfl) ---
#pragma unroll
    for (int m = 0; m < 4; ++m) {
#pragma unroll
        for (int r = 0; r < 4; ++r) {
            int rowlane = 16 * m + kg * 4 + r;
            int pp = __shfl(mypos, rowlane);
            if (pp != 0xFF) {
#pragma unroll
                for (int n = 0; n < 2; ++n) {
                    int col = 32 * wc + 16 * n + fr;
                    unsigned bb = f2bf(acc[m][n][r]);
                    unsigned su = bb ^ ((bb >> 15) ? 0xFFFFu : 0x8000u);
                    proj16[pp * 128 + col] = (unsigned short)su;
                }
            }
        }
    }
    __syncthreads();

    // --- phase 2: ranking via sortable-u32 keys, 2 passes x 16 keys ---
    const int mmv = min(n0, n1);      // <= 64 since n0+n1 <= 128
    const int c = tid & 127;
    const int q = tid >> 7;           // 0..3
#pragma unroll
    for (int pass = 0; pass < 2; ++pass) {
        const int pbase = q * 32 + pass * 16;
        unsigned kv[16];
        int cnt[16];
#pragma unroll
        for (int ii = 0; ii < 16; ++ii) {
            int p = pbase + ii;
            unsigned key = 0xFFFFFFFFu;
            if (p < ntot) {
                unsigned su = proj16[p * 128 + c];
                key = ((unsigned)(p >= n0) << 31) | (su << 8) | (unsigned)p;
            }
            kv[ii] = key;
            cnt[ii] = 0;
        }
        int lo, hi;
        if (pbase + 16 <= n0) { lo = 0;  hi = n0;   }   // pure group-0 chunk
        else if (pbase >= n0) { lo = n0; hi = ntot; }   // pure group-1 chunk
        else                  { lo = 0;  hi = ntot; }   // straddler
        for (int j = lo; j < hi; ++j) {
            unsigned su = proj16[j * 128 + c];
            unsigned kw = ((unsigned)(j >= n0) << 31) | (su << 8) | (unsigned)j;
#pragma unroll
            for (int ii = 0; ii < 16; ++ii) cnt[ii] += (kw < kv[ii]) ? 1 : 0;
        }
#pragma unroll
        for (int ii = 0; ii < 16; ++ii) {
            int p = pbase + ii;
            if (p < ntot) {
                int rank = cnt[ii] - ((p >= n0 && lo == 0) ? n0 : 0);
                if (rank < mmv) {
                    unsigned char* buf = (p >= n0) ? yb : xb;
                    buf[rank * 128 + c] = (unsigned char)p;
                }
            }
        }
    }
    __syncthreads();

    // --- phase 3: paired diff per column, max over columns ---
    float part = 0.f;
    for (int r = q; r < mmv; r += 4) {
        unsigned sx = proj16[(int)xb[r * 128 + c] * 128 + c];
        unsigned sy = proj16[(int)yb[r * 128 + c] * 128 + c];
        unsigned bx = sx ^ ((sx >> 15) ? 0x8000u : 0xFFFFu);
        unsigned byv = sy ^ ((sy >> 15) ? 0x8000u : 0xFFFFu);
        part += fabsf(bf2f((unsigned short)bx) - bf2f((unsigned short)byv));
    }
    dred[tid] = part;
    __syncthreads();
    if (tid < 128) {
        float invm = 1.f / (float)max(mmv, 1);
        dred[tid] = (dred[tid] + dred[tid + 128] + dred[tid + 256] + dred[tid + 384]) * invm;
    }
    __syncthreads();
    if (tid < 64) {
        float m = fmaxf(dred[tid], dred[tid + 64]);
#pragma unroll
        for (int off = 32; off > 0; off >>= 1) m = fmaxf(m, __shfl_xor(m, off));
        if (tid == 0) d_ot[b] = m;    // one block per batch: direct store
    }
}

// ---------------------------------------------------------------------------
// Kernel 3: head — C/S GEMV + gate + LayerNorm + logits.
// 320 threads (1 output each), 4 batches per block, wave-parallel LN.
// ---------------------------------------------------------------------------
__global__ __launch_bounds__(320) void k_head(const float* __restrict__ rep,
                                              const float* __restrict__ Wc,
                                              const float* __restrict__ bc,
                                              const float* __restrict__ Ws,
                                              const float* __restrict__ bs,
                                              const float* __restrict__ gate,
                                              const float* __restrict__ lng,
                                              const float* __restrict__ lnb,
                                              const float* __restrict__ Wcls,
                                              const float* __restrict__ bcls,
                                              const float* __restrict__ d_ot,
                                              float* __restrict__ out) {
    int b0 = blockIdx.x * 4;
    int tid = threadIdx.x;
    __shared__ __align__(16) float repS[4 * 1536];
    __shared__ float featS[4 * FEAT_];

    const float4* repg = reinterpret_cast<const float4*>(rep + (size_t)b0 * 1536);
    float4* repl = reinterpret_cast<float4*>(repS);
    for (int i = tid; i < 1536; i += 320) repl[i] = repg[i];
    __syncthreads();

    float g = 1.f / (1.f + expf(-gate[0]));

    {
        int o = tid;  // 0..319
        bool isC = o < CD_;
        const float* wptr = isC ? (Wc + (size_t)o * 1536) : (Ws + (size_t)(o - CD_) * 1536);
        float bias = isC ? bc[o] : bs[o - CD_];
        float scale = isC ? (1.f - g) : g;
        const float4* w4 = reinterpret_cast<const float4*>(wptr);
        float a0 = 0.f, a1 = 0.f, a2 = 0.f, a3 = 0.f;
        for (int k4 = 0; k4 < 384; ++k4) {
            float4 wv = w4[k4];
            float4 r0 = repl[k4];
            float4 r1 = repl[384 + k4];
            float4 r2 = repl[768 + k4];
            float4 r3 = repl[1152 + k4];
            a0 += fmaf(wv.x, r0.x, fmaf(wv.y, r0.y, fmaf(wv.z, r0.z, wv.w * r0.w)));
            a1 += fmaf(wv.x, r1.x, fmaf(wv.y, r1.y, fmaf(wv.z, r1.z, wv.w * r1.w)));
            a2 += fmaf(wv.x, r2.x, fmaf(wv.y, r2.y, fmaf(wv.z, r2.z, wv.w * r2.w)));
            a3 += fmaf(wv.x, r3.x, fmaf(wv.y, r3.y, fmaf(wv.z, r3.z, wv.w * r3.w)));
        }
        featS[0 * FEAT_ + o] = (a0 + bias) * scale;
        featS[1 * FEAT_ + o] = (a1 + bias) * scale;
        featS[2 * FEAT_ + o] = (a2 + bias) * scale;
        featS[3 * FEAT_ + o] = (a3 + bias) * scale;
    }
    if (tid < 4) featS[tid * FEAT_ + 320] = d_ot[b0 + tid];
    __syncthreads();

    int w = tid >> 6, lane = tid & 63;
    if (w < 4) {   // wave w handles batch b0+w
        const float* f = featS + w * FEAT_;
        float s = 0.f, s2 = 0.f;
        for (int i = lane; i < FEAT_; i += 64) {
            float v = f[i];
            s += v;
            s2 = fmaf(v, v, s2);
        }
#pragma unroll
        for (int off = 32; off > 0; off >>= 1) {
            s += __shfl_xor(s, off);
            s2 += __shfl_xor(s2, off);
        }
        float mu = s * (1.f / (float)FEAT_);
        float var = fmaxf(s2 * (1.f / (float)FEAT_) - mu * mu, 0.f);
        float rstd = 1.0f / sqrtf(var + LN_EPS_);
        float l0 = 0.f, l1 = 0.f;
        for (int i = lane; i < FEAT_; i += 64) {
            float nv = (f[i] - mu) * rstd * lng[i] + lnb[i];
            l0 = fmaf(nv, Wcls[i], l0);
            l1 = fmaf(nv, Wcls[FEAT_ + i], l1);
        }
#pragma unroll
        for (int off = 32; off > 0; off >>= 1) {
            l0 += __shfl_xor(l0, off);
            l1 += __shfl_xor(l1, off);
        }
        if (lane == 0) {
            out[(size_t)(b0 + w) * 2 + 0] = l0 + bcls[0];
            out[(size_t)(b0 + w) * 2 + 1] = l1 + bcls[1];
        }
    }
}

// ---------------------------------------------------------------------------
// Kernel 4/5: ortho = mean((Wc @ Ws^T)^2)
// ---------------------------------------------------------------------------
__global__ __launch_bounds__(256) void k_ortho(const float* __restrict__ Wc,
                                               const float* __restrict__ Ws,
                                               float* __restrict__ part) {
    int i = blockIdx.x;
    int tid = threadIdx.x;
    __shared__ float wrow[1536];
    __shared__ float tmp[256];
    for (int k = tid; k < 1536; k += 256) wrow[k] = Wc[(size_t)i * 1536 + k];
    __syncthreads();
    int j = tid & 127, h = tid >> 7;
    const float* wsr = Ws + (size_t)j * 1536 + h * 768;
    const float* wr = wrow + h * 768;
    float s = 0.f;
    for (int k = 0; k < 768; ++k) s = fmaf(wr[k], wsr[k], s);
    tmp[tid] = s;
    __syncthreads();
    if (tid < 128) {
        float d = tmp[tid] + tmp[tid + 128];
        tmp[tid] = d * d;
    }
    __syncthreads();
    for (int off = 64; off > 0; off >>= 1) {
        if (tid < off) tmp[tid] += tmp[tid + off];
        __syncthreads();
    }
    if (tid == 0) part[i] = tmp[0];
}

__global__ __launch_bounds__(256) void k_ortho2(const float* __restrict__ part,
                                                float* __restrict__ out) {
    int tid = threadIdx.x;
    __shared__ float red[256];
    red[tid] = (tid < CD_) ? part[tid] : 0.f;
    __syncthreads();
    for (int off = 128; off > 0; off >>= 1) {
        if (tid < off) red[tid] += red[tid + off];
        __syncthreads();
    }
    if (tid == 0) out[(size_t)B_ * 2] = red[0] / (float)(CD_ * SD_);
}

// ---------------------------------------------------------------------------
extern "C" void kernel_launch(void* const* d_in, const int* in_sizes, int n_in,
                              void* d_out, int out_size, void* d_ws, size_t ws_size,
                              hipStream_t stream) {
    const float* H    = (const float*)d_in[0];
    const int*   tt   = (const int*)d_in[1];
    const int*   attn = (const int*)d_in[2];
    const float* Wc   = (const float*)d_in[3];
    const float* bc   = (const float*)d_in[4];
    const float* Ws   = (const float*)d_in[5];
    const float* bs   = (const float*)d_in[6];
    const float* gate = (const float*)d_in[7];
    const float* lng  = (const float*)d_in[8];
    const float* lnb  = (const float*)d_in[9];
    const float* Wcls = (const float*)d_in[10];
    const float* bcls = (const float*)d_in[11];
    const float* dirs = (const float*)d_in[12];

    float* ws    = (float*)d_ws;
    float* rep   = ws;                                      // [B][1536] fp32
    unsigned short* dn16 = (unsigned short*)(ws + REP_SZ);  // [P][D] bf16 row-major
    float* dot   = ws + REP_SZ + DN16_FLT;                  // [B]
    float* part  = dot + B_;                                // [CD]
    float* out   = (float*)d_out;

    k_dirs<<<P_, 256, 0, stream>>>(dirs, dn16);
    k_projsort<<<B_, 512, 0, stream>>>(H, tt, attn, dn16, rep, dot);
    k_head<<<B_ / 4, 320, 0, stream>>>(rep, Wc, bc, Ws, bs, gate, lng, lnb, Wcls, bcls, dot, out);
    k_ortho<<<CD_, 256, 0, stream>>>(Wc, Ws, part);
    k_ortho2<<<1, 256, 0, stream>>>(part, out);
}